// Round 7
// baseline (306.704 us; speedup 1.0000x reference)
//
#include <hip/hip_runtime.h>
#include <hip/hip_bf16.h>
#include <hip/hip_fp16.h>

typedef unsigned int u32;
typedef unsigned short u16;
typedef _Float16 f16;

static constexpr int HWn = 65536;
static constexpr int NCOPY = 32;

typedef __attribute__((ext_vector_type(8))) f16 f16x8;
typedef __attribute__((ext_vector_type(4))) float f32x4;

__device__ __forceinline__ float h2f(u16 u) {
    union { u16 s; f16 h; } z; z.s = u; return (float)z.h;
}
__device__ __forceinline__ u16 f2h(float f) {
    union { u16 s; f16 h; } z; z.h = (f16)f; return z.s;
}
__device__ __forceinline__ u32 pack2h(float a, float b) {
    union { u32 i; f16 h[2]; } z; z.h[0] = (f16)a; z.h[1] = (f16)b; return z.i;
}
__device__ __forceinline__ float hlo(u32 u) {
    union { u32 i; f16 h[2]; } z; z.i = u; return (float)z.h[0];
}
__device__ __forceinline__ float hhi(u32 u) {
    union { u32 i; f16 h[2]; } z; z.i = u; return (float)z.h[1];
}
__device__ __forceinline__ float sq2h(u32 a) {
    const float l = hlo(a), h = hhi(a);
    return fmaf(l, l, h * h);
}

// Swizzled LDS offset (u16 units) for transposed X tile: [px 0..127][ic 0..95]
__device__ __forceinline__ int xoff(int px, int icb) {
    return px * 128 + (((icb ^ (px & 7) ^ ((px >> 3) & 7))) << 3);
}

// Convert conv1x1 weights to f16, layout [row 0..287][ic 0..95]
__global__ __launch_bounds__(256) void k_prep_w(
    const float* __restrict__ wq, const float* __restrict__ wkv,
    u16* __restrict__ wf)
{
    const int i = blockIdx.x * 256 + threadIdx.x;
    if (i >= 288 * 96) return;
    const int row = i / 96, ic = i % 96;
    const float w = (row < 96) ? wq[row * 96 + ic] : wkv[(row - 96) * 96 + ic];
    wf[i] = f2h(w);
}

// K1: conv1x1 via f16 MFMA. grid (512 px-tiles, 2 sec {q, kv}, 4 b), 256 thr.
__global__ __launch_bounds__(256, 5) void k_conv_mfma(
    const float* __restrict__ ff, const float* __restrict__ x,
    const u16* __restrict__ wf,
    u16* __restrict__ qpre, u16* __restrict__ kvpre)
{
    const int b = blockIdx.z, sec = blockIdx.y;
    const int px0 = blockIdx.x * 128;
    const int tid = threadIdx.x;

    __shared__ __align__(16) u16 xs[16384];     // 32 KB, f16 bits

    const float* src = (sec == 0 ? ff : x) + (size_t)b * 96 * HWn;

    // stage: ic pair = (p*32 + (tid>>4)*2, +1), px run of 8 at (tid&15)*8
    const int icq = (tid >> 4) * 2;
    const int pxs = (tid & 15) * 8;
    #pragma unroll
    for (int p = 0; p < 3; ++p) {
        const int ic = p * 32 + icq;
        const float* rp0 = src + (size_t)ic * HWn + px0 + pxs;
        const float* rp1 = rp0 + HWn;
        const float4 a0 = *reinterpret_cast<const float4*>(rp0);
        const float4 a1 = *reinterpret_cast<const float4*>(rp0 + 4);
        const float4 b0 = *reinterpret_cast<const float4*>(rp1);
        const float4 b1 = *reinterpret_cast<const float4*>(rp1 + 4);
        const int icb = ic >> 3, icl = ic & 7;
        const float e0[8] = {a0.x, a0.y, a0.z, a0.w, a1.x, a1.y, a1.z, a1.w};
        const float e1[8] = {b0.x, b0.y, b0.z, b0.w, b1.x, b1.y, b1.z, b1.w};
        #pragma unroll
        for (int j = 0; j < 8; ++j) {
            const int o = xoff(pxs + j, icb) + icl;   // even
            *reinterpret_cast<u32*>(&xs[o]) = pack2h(e0[j], e1[j]);
        }
    }
    __syncthreads();

    const int lane = tid & 63;
    const int wv = tid >> 6;
    const int oc0 = (wv >> 1) * 48;
    const int pxw = (wv & 1) * 64;
    const int lr = lane & 15, lg = lane >> 4;

    const int npass = (sec == 0) ? 1 : 2;
    #pragma unroll 1
    for (int kvs = 0; kvs < npass; ++kvs) {
        const u16* wh = wf + ((sec == 0) ? 0 : (96 + kvs * 96)) * 96;
        u16* dst = (sec == 0) ? (qpre + (size_t)b * 96 * HWn)
                              : (kvpre + (size_t)b * 192 * HWn + (size_t)kvs * 96 * HWn);

        f32x4 acc[3][4];
        #pragma unroll
        for (int m = 0; m < 3; ++m)
            #pragma unroll
            for (int n = 0; n < 4; ++n)
                acc[m][n] = (f32x4){0.f, 0.f, 0.f, 0.f};

        #pragma unroll 1
        for (int kt = 0; kt < 3; ++kt) {
            const int kb = kt * 32;
            f16x8 B[4];
            #pragma unroll
            for (int n = 0; n < 4; ++n)
                B[n] = *(const f16x8*)(xs + xoff(pxw + n * 16 + lr, (kb >> 3) + lg));
            f16x8 A[3];
            #pragma unroll
            for (int m = 0; m < 3; ++m)
                A[m] = *(const f16x8*)(wh + (oc0 + m * 16 + lr) * 96 + kb + lg * 8);
            #pragma unroll
            for (int m = 0; m < 3; ++m)
                #pragma unroll
                for (int n = 0; n < 4; ++n)
                    acc[m][n] = __builtin_amdgcn_mfma_f32_16x16x32_f16(A[m], B[n], acc[m][n], 0, 0, 0);
        }

        #pragma unroll
        for (int m = 0; m < 3; ++m) {
            #pragma unroll
            for (int i = 0; i < 4; ++i) {
                const int oc = oc0 + m * 16 + lg * 4 + i;
                u16* drow = dst + (size_t)oc * HWn + px0;
                #pragma unroll
                for (int n = 0; n < 4; ++n)
                    drow[pxw + n * 16 + lr] = f2h(acc[m][n][i]);
            }
        }
    }
}

__device__ __forceinline__ void dw_addr(
    int it, int pq, int b,
    const u16* qpre, const u16* kvpre, const float* wqdw, const float* wkvdw,
    const u16*& src, const float*& wp, int& c, int& seg)
{
    const int p = it * 32 + pq;
    if (p < 96)       { c = p;       src = qpre  + ((size_t)(b * 96 + c)) * HWn;       wp = wqdw  + c * 9; seg = 0; }
    else if (p < 192) { c = p - 96;  src = kvpre + ((size_t)(b * 192 + c)) * HWn;      wp = wkvdw + c * 9; seg = 1; }
    else              { c = p - 192; src = kvpre + ((size_t)(b * 192 + 96 + c)) * HWn; wp = wkvdw + (96 + c) * 9; seg = 2; }
}

// K2: fused depthwise 3x3 + reductions, with 1-deep register prefetch across
// plane iterations and low-contention partial accumulators for S/ssq.
__global__ __launch_bounds__(512) void k_dw_fused(
    const u16* __restrict__ qpre, const u16* __restrict__ kvpre,
    const float* __restrict__ wqdw, const float* __restrict__ wkvdw,
    u16* __restrict__ vout, float* __restrict__ ssqp, float* __restrict__ Spart)
{
    const int bid = blockIdx.x;                  // 0..2047
    const int wg = (bid & 7) * 256 + (bid >> 3); // XCD: contiguous y span per XCD
    const int copy = bid & (NCOPY - 1);
    const int b = wg >> 9;
    const int rem = wg & 511;
    const int y = rem >> 1;
    const int tx = (rem & 1) * 128;
    const int tid = threadIdx.x;
    const int lane = tid & 63;
    const int pq = tid >> 4;
    const int chunk = tid & 15;
    const int x0l = chunk * 8;
    const int xg = tx + x0l;

    const bool vr0 = (y > 0), vr2 = (y < 255);   // block-uniform
    const bool le = (chunk == 0) && (xg > 0);
    const bool re = (chunk == 15) && (xg + 8 < 256);

    __shared__ __align__(16) u16 qs[96][136];
    __shared__ __align__(16) u16 ks[96][136];

    auto issue = [&](const u16* src, uint4* m, u32* el, u32* er) {
        const uint4 z = make_uint4(0u, 0u, 0u, 0u);
        const u16* r0 = src + (y - 1) * 256 + xg;
        const u16* r1 = r0 + 256;
        const u16* r2 = r1 + 256;
        m[0] = vr0 ? *reinterpret_cast<const uint4*>(r0) : z;
        m[1] = *reinterpret_cast<const uint4*>(r1);
        m[2] = vr2 ? *reinterpret_cast<const uint4*>(r2) : z;
        el[0] = (le && vr0) ? r0[-1] : 0u;  er[0] = (re && vr0) ? r0[8] : 0u;
        el[1] = le ? r1[-1] : 0u;           er[1] = re ? r1[8] : 0u;
        el[2] = (le && vr2) ? r2[-1] : 0u;  er[2] = (re && vr2) ? r2[8] : 0u;
    };

    // prologue: issue iteration 0
    const u16* srcC; const float* wpC; int cC, segC;
    dw_addr(0, pq, b, qpre, kvpre, wqdw, wkvdw, srcC, wpC, cC, segC);
    uint4 mcur[3]; u32 elc[3], erc[3];
    issue(srcC, mcur, elc, erc);

    #pragma unroll 1
    for (int it = 0; it < 9; ++it) {
        const u16* srcN; const float* wpN; int cN, segN;
        uint4 mnx[3]; u32 eln[3], ern[3];
        if (it < 8) {
            dw_addr(it + 1, pq, b, qpre, kvpre, wqdw, wkvdw, srcN, wpN, cN, segN);
            issue(srcN, mnx, eln, ern);
        }

        float a0 = 0.f, a1 = 0.f, a2 = 0.f, a3 = 0.f, a4 = 0.f, a5 = 0.f, a6 = 0.f, a7 = 0.f;
        #pragma unroll
        for (int r = 0; r < 3; ++r) {
            const uint4 m = mcur[r];
            const float v1 = hlo(m.x), v2 = hhi(m.x);
            const float v3 = hlo(m.y), v4 = hhi(m.y);
            const float v5 = hlo(m.z), v6 = hhi(m.z);
            const float v7 = hlo(m.w), v8 = hhi(m.w);
            const float lv = __shfl(v8, (lane - 1) & 63);
            const float rv = __shfl(v1, (lane + 1) & 63);
            const float v0 = (chunk == 0)  ? h2f((u16)elc[r]) : lv;
            const float v9 = (chunk == 15) ? h2f((u16)erc[r]) : rv;
            const float w0 = wpC[r * 3 + 0], w1 = wpC[r * 3 + 1], w2 = wpC[r * 3 + 2];
            a0 = fmaf(w0, v0, fmaf(w1, v1, fmaf(w2, v2, a0)));
            a1 = fmaf(w0, v1, fmaf(w1, v2, fmaf(w2, v3, a1)));
            a2 = fmaf(w0, v2, fmaf(w1, v3, fmaf(w2, v4, a2)));
            a3 = fmaf(w0, v3, fmaf(w1, v4, fmaf(w2, v5, a3)));
            a4 = fmaf(w0, v4, fmaf(w1, v5, fmaf(w2, v6, a4)));
            a5 = fmaf(w0, v5, fmaf(w1, v6, fmaf(w2, v7, a5)));
            a6 = fmaf(w0, v6, fmaf(w1, v7, fmaf(w2, v8, a6)));
            a7 = fmaf(w0, v7, fmaf(w1, v8, fmaf(w2, v9, a7)));
        }

        const uint4 o = make_uint4(pack2h(a0, a1), pack2h(a2, a3), pack2h(a4, a5), pack2h(a6, a7));
        if (segC == 0) {
            *reinterpret_cast<uint4*>(&qs[cC][x0l]) = o;
        } else if (segC == 1) {
            *reinterpret_cast<uint4*>(&ks[cC][x0l]) = o;
        } else {
            *reinterpret_cast<uint4*>(vout + ((size_t)(b * 96 + cC)) * HWn + y * 256 + xg) = o;
        }

        if (it < 8) {
            #pragma unroll
            for (int r = 0; r < 3; ++r) { mcur[r] = mnx[r]; elc[r] = eln[r]; erc[r] = ern[r]; }
            wpC = wpN; cC = cN; segC = segN;
        }
    }
    __syncthreads();

    // ssq: 192 rows x 2 halves (64 px) = 384 tasks -> partial copy accumulators
    if (tid < 384) {
        const int half = tid >= 192;
        const int r = tid - half * 192;
        const uint4* rr = reinterpret_cast<const uint4*>(
            (r < 96 ? &qs[r][0] : &ks[r - 96][0]) + half * 64);
        float s = 0.f;
        #pragma unroll
        for (int pch = 0; pch < 8; ++pch) {
            const uint4 a = rr[pch];
            s += sq2h(a.x) + sq2h(a.y) + sq2h(a.z) + sq2h(a.w);
        }
        atomicAdd(ssqp + (copy * 4 + b) * 192 + r, s);
    }

    // S via f16 MFMA: wave w -> head h = w&3, row-tile mt = w>>2.
    {
        const int w = tid >> 6;
        const int h = w & 3, mt = w >> 2;
        const int lr2 = lane & 15, lg2 = lane >> 4;
        const int ar = h * 24 + min(mt * 16 + lr2, 23);  // clamp-dup, discard on store
        f32x4 acc2[2];
        acc2[0] = (f32x4){0.f, 0.f, 0.f, 0.f};
        acc2[1] = (f32x4){0.f, 0.f, 0.f, 0.f};
        #pragma unroll
        for (int ks4 = 0; ks4 < 4; ++ks4) {
            const f16x8 A = *(const f16x8*)(&qs[ar][ks4 * 32 + lg2 * 8]);
            #pragma unroll
            for (int nt = 0; nt < 2; ++nt) {
                const int bc = h * 24 + min(nt * 16 + lr2, 23);
                const f16x8 B = *(const f16x8*)(&ks[bc][ks4 * 32 + lg2 * 8]);
                acc2[nt] = __builtin_amdgcn_mfma_f32_16x16x32_f16(A, B, acc2[nt], 0, 0, 0);
            }
        }
        float* Sdst = Spart + (copy * 4 + b) * 2304 + h * 576;
        #pragma unroll
        for (int nt = 0; nt < 2; ++nt) {
            const int col = nt * 16 + lr2;
            #pragma unroll
            for (int reg = 0; reg < 4; ++reg) {
                const int row24 = mt * 16 + lg2 * 4 + reg;
                if (row24 < 24 && col < 24)
                    atomicAdd(Sdst + row24 * 24 + col, acc2[nt][reg]);
            }
        }
    }
}

// K3: sum partials, normalize, softmax, fold w_out -> Mf [oc][dg] f16
__global__ __launch_bounds__(256) void k_attn_fold(
    const float* __restrict__ Spart, const float* __restrict__ ssqp,
    const float* __restrict__ temp, const float* __restrict__ w_out,
    u16* __restrict__ mf)
{
    const int b = blockIdx.x;
    const int tid = threadIdx.x;
    __shared__ float rq[96], rk[96], att[2304];

    for (int v = tid; v < 2304; v += 256) {
        float s = 0.f;
        #pragma unroll 4
        for (int cp = 0; cp < NCOPY; ++cp) s += Spart[(cp * 4 + b) * 2304 + v];
        att[v] = s;
    }
    if (tid < 192) {
        float s = 0.f;
        #pragma unroll 4
        for (int cp = 0; cp < NCOPY; ++cp) s += ssqp[(cp * 4 + b) * 192 + tid];
        const float r = 1.f / fmaxf(sqrtf(s), 1e-12f);
        if (tid < 96) rq[tid] = r; else rk[tid - 96] = r;
    }
    __syncthreads();

    if (tid < 96) {
        const int h = tid / 24, i = tid % 24;
        const float tmp = temp[h];
        const float rqi = rq[h * 24 + i];
        float l[24];
        float m = -1e30f;
        #pragma unroll
        for (int j = 0; j < 24; ++j) {
            l[j] = att[(h * 24 + i) * 24 + j] * rqi * rk[h * 24 + j] * tmp;
            m = fmaxf(m, l[j]);
        }
        float ssum = 0.f;
        #pragma unroll
        for (int j = 0; j < 24; ++j) { l[j] = expf(l[j] - m); ssum += l[j]; }
        const float inv = 1.f / ssum;
        #pragma unroll
        for (int j = 0; j < 24; ++j) att[(h * 24 + i) * 24 + j] = l[j] * inv;
    }
    __syncthreads();

    for (int k = 0; k < 36; ++k) {
        const int id = k * 256 + tid;
        const int dg = id / 96, oc = id % 96;
        const int h = dg / 24, d24 = dg % 24;
        float s = 0.f;
        #pragma unroll
        for (int i = 0; i < 24; ++i) {
            s += w_out[oc * 96 + h * 24 + i] * att[(h * 24 + i) * 24 + d24];
        }
        mf[b * 9216 + oc * 96 + dg] = f2h(s);
    }
}

// K4: out = M @ v via f16 MFMA. grid (512 px-tiles, 4 b), 256 thr, 32 KB LDS.
__global__ __launch_bounds__(256, 5) void k_out_mfma(
    const u16* __restrict__ v, const u16* __restrict__ mf,
    float* __restrict__ out)
{
    const int b = blockIdx.y;
    const int px0 = blockIdx.x * 128;
    const int tid = threadIdx.x;
    __shared__ __align__(16) u16 xt[16384];

    const u16* vb = v + (size_t)b * 96 * HWn;
    const u16* mh = mf + b * 9216;

    const int icq = (tid >> 4) * 2;
    const int pxs = (tid & 15) * 8;
    #pragma unroll
    for (int p = 0; p < 3; ++p) {
        const int dg = p * 32 + icq;
        const uint4 u0 = *reinterpret_cast<const uint4*>(vb + (size_t)dg * HWn + px0 + pxs);
        const uint4 u1 = *reinterpret_cast<const uint4*>(vb + (size_t)(dg + 1) * HWn + px0 + pxs);
        const u32 w0[4] = {u0.x, u0.y, u0.z, u0.w};
        const u32 w1[4] = {u1.x, u1.y, u1.z, u1.w};
        const int icb = dg >> 3, icl = dg & 7;
        #pragma unroll
        for (int j = 0; j < 8; ++j) {
            const u32 lo = (w0[j >> 1] >> ((j & 1) * 16)) & 0xffffu;
            const u32 hi = (w1[j >> 1] >> ((j & 1) * 16)) & 0xffffu;
            const int o = xoff(pxs + j, icb) + icl;      // even
            *reinterpret_cast<u32*>(&xt[o]) = (hi << 16) | lo;
        }
    }
    __syncthreads();

    const int lane = tid & 63;
    const int wv = tid >> 6;
    const int oc0 = (wv >> 1) * 48;
    const int pxw = (wv & 1) * 64;
    const int lr = lane & 15, lg = lane >> 4;

    f32x4 acc[3][4];
    #pragma unroll
    for (int m = 0; m < 3; ++m)
        #pragma unroll
        for (int n = 0; n < 4; ++n)
            acc[m][n] = (f32x4){0.f, 0.f, 0.f, 0.f};

    #pragma unroll 1
    for (int kt = 0; kt < 3; ++kt) {
        const int kb = kt * 32;
        f16x8 B[4];
        #pragma unroll
        for (int n = 0; n < 4; ++n)
            B[n] = *(const f16x8*)(xt + xoff(pxw + n * 16 + lr, (kb >> 3) + lg));
        f16x8 A[3];
        #pragma unroll
        for (int m = 0; m < 3; ++m)
            A[m] = *(const f16x8*)(mh + (oc0 + m * 16 + lr) * 96 + kb + lg * 8);
        #pragma unroll
        for (int m = 0; m < 3; ++m)
            #pragma unroll
            for (int n = 0; n < 4; ++n)
                acc[m][n] = __builtin_amdgcn_mfma_f32_16x16x32_f16(A[m], B[n], acc[m][n], 0, 0, 0);
    }

    #pragma unroll
    for (int m = 0; m < 3; ++m) {
        #pragma unroll
        for (int i = 0; i < 4; ++i) {
            const int oc = oc0 + m * 16 + lg * 4 + i;
            float* drow = out + ((size_t)(b * 96 + oc)) * HWn + px0;
            #pragma unroll
            for (int n = 0; n < 4; ++n)
                drow[pxw + n * 16 + lr] = acc[m][n][i];
        }
    }
}

extern "C" void kernel_launch(void* const* d_in, const int* in_sizes, int n_in,
                              void* d_out, int out_size, void* d_ws, size_t ws_size,
                              hipStream_t stream) {
    (void)in_sizes; (void)n_in; (void)out_size; (void)ws_size;
    const float* x      = (const float*)d_in[0];
    const float* ff     = (const float*)d_in[1];
    const float* w_q    = (const float*)d_in[2];
    const float* w_kv   = (const float*)d_in[3];
    const float* w_q_dw = (const float*)d_in[4];
    const float* w_kv_dw= (const float*)d_in[5];
    const float* w_out  = (const float*)d_in[6];
    const float* temp   = (const float*)d_in[7];
    float* out = (float*)d_out;

    char* ws = (char*)d_ws;
    u16* qpre   = (u16*)(ws);                      //  50,331,648 B
    u16* kvpre  = (u16*)(ws + 50331648);           // 100,663,296 B
    u16* vbuf   = (u16*)(ws + 150994944);          //  50,331,648 B
    float* Spart= (float*)(ws + 201326592);        //   1,179,648 B (32 copies x 4 b x 2304)
    float* ssqp = (float*)(ws + 202506240);        //      98,304 B (32 copies x 4 b x 192)
    u16* wf     = (u16*)(ws + 202604544);          //      55,296 B
    u16* mf     = (u16*)(ws + 202659840);          //      73,728 B

    hipMemsetAsync(ws + 201326592, 0, 1179648 + 98304, stream);

    k_prep_w<<<108, 256, 0, stream>>>(w_q, w_kv, wf);
    k_conv_mfma<<<dim3(512, 2, 4), 256, 0, stream>>>(ff, x, wf, qpre, kvpre);
    k_dw_fused<<<dim3(2048), 512, 0, stream>>>(qpre, kvpre, w_q_dw, w_kv_dw, vbuf, ssqp, Spart);
    k_attn_fold<<<4, 256, 0, stream>>>(Spart, ssqp, temp, w_out, mf);
    k_out_mfma<<<dim3(512, 4), 256, 0, stream>>>(vbuf, mf, out);
}

// Round 8
// 272.955 us; speedup vs baseline: 1.1236x; 1.1236x over previous
//
#include <hip/hip_runtime.h>
#include <hip/hip_bf16.h>
#include <hip/hip_fp16.h>

typedef unsigned int u32;
typedef unsigned short u16;
typedef _Float16 f16;

static constexpr int HWn = 65536;

typedef __attribute__((ext_vector_type(8))) f16 f16x8;
typedef __attribute__((ext_vector_type(2))) f16 f16x2;
typedef __attribute__((ext_vector_type(4))) float f32x4;

__device__ __forceinline__ float h2f(u16 u) {
    union { u16 s; f16 h; } z; z.s = u; return (float)z.h;
}
__device__ __forceinline__ u16 f2h(float f) {
    union { u16 s; f16 h; } z; z.h = (f16)f; return z.s;
}
__device__ __forceinline__ u32 pack2h(float a, float b) {
    union { u32 i; f16 h[2]; } z; z.h[0] = (f16)a; z.h[1] = (f16)b; return z.i;
}
__device__ __forceinline__ float hlo(u32 u) {
    union { u32 i; f16 h[2]; } z; z.i = u; return (float)z.h[0];
}
__device__ __forceinline__ float hhi(u32 u) {
    union { u32 i; f16 h[2]; } z; z.i = u; return (float)z.h[1];
}
__device__ __forceinline__ float sq2h(u32 a) {
    const float l = hlo(a), h = hhi(a);
    return fmaf(l, l, h * h);
}

#if defined(__has_builtin)
#if __has_builtin(__builtin_amdgcn_fdot2)
#define HAS_FDOT2 1
#endif
#endif
// d = a.lo*b.lo + a.hi*b.hi + c, f32 accumulate (v_dot2_f32_f16)
__device__ __forceinline__ float fdot2a(u32 a, u32 b, float c) {
#ifdef HAS_FDOT2
    union { u32 i; f16x2 h; } A, B; A.i = a; B.i = b;
    return __builtin_amdgcn_fdot2(A.h, B.h, c, false);
#else
    return fmaf(hlo(a), hlo(b), fmaf(hhi(a), hhi(b), c));
#endif
}

// Swizzled LDS offset (u16 units) for transposed X tile: [px 0..127][ic 0..95]
__device__ __forceinline__ int xoff(int px, int icb) {
    return px * 128 + (((icb ^ (px & 7) ^ ((px >> 3) & 7))) << 3);
}

// Convert conv1x1 weights to f16, layout [row 0..287][ic 0..95]
__global__ __launch_bounds__(256) void k_prep_w(
    const float* __restrict__ wq, const float* __restrict__ wkv,
    u16* __restrict__ wf)
{
    const int i = blockIdx.x * 256 + threadIdx.x;
    if (i >= 288 * 96) return;
    const int row = i / 96, ic = i % 96;
    const float w = (row < 96) ? wq[row * 96 + ic] : wkv[(row - 96) * 96 + ic];
    wf[i] = f2h(w);
}

// K1: conv1x1 via f16 MFMA. grid (512 px-tiles, 2 sec {q, kv}, 4 b), 256 thr.
__global__ __launch_bounds__(256, 5) void k_conv_mfma(
    const float* __restrict__ ff, const float* __restrict__ x,
    const u16* __restrict__ wf,
    u16* __restrict__ qpre, u16* __restrict__ kvpre)
{
    const int b = blockIdx.z, sec = blockIdx.y;
    const int px0 = blockIdx.x * 128;
    const int tid = threadIdx.x;

    __shared__ __align__(16) u16 xs[16384];     // 32 KB, f16 bits

    const float* src = (sec == 0 ? ff : x) + (size_t)b * 96 * HWn;

    const int icq = (tid >> 4) * 2;
    const int pxs = (tid & 15) * 8;
    #pragma unroll 1
    for (int p = 0; p < 3; ++p) {
        const int ic = p * 32 + icq;
        const float* rp0 = src + (size_t)ic * HWn + px0 + pxs;
        const float* rp1 = rp0 + HWn;
        const float4 a0 = *reinterpret_cast<const float4*>(rp0);
        const float4 a1 = *reinterpret_cast<const float4*>(rp0 + 4);
        const float4 b0 = *reinterpret_cast<const float4*>(rp1);
        const float4 b1 = *reinterpret_cast<const float4*>(rp1 + 4);
        const int icb = ic >> 3, icl = ic & 7;
        const float e0[8] = {a0.x, a0.y, a0.z, a0.w, a1.x, a1.y, a1.z, a1.w};
        const float e1[8] = {b0.x, b0.y, b0.z, b0.w, b1.x, b1.y, b1.z, b1.w};
        #pragma unroll
        for (int j = 0; j < 8; ++j) {
            const int o = xoff(pxs + j, icb) + icl;   // even
            *reinterpret_cast<u32*>(&xs[o]) = pack2h(e0[j], e1[j]);
        }
    }
    __syncthreads();

    const int lane = tid & 63;
    const int wv = tid >> 6;
    const int oc0 = (wv >> 1) * 48;
    const int pxw = (wv & 1) * 64;
    const int lr = lane & 15, lg = lane >> 4;

    const int npass = (sec == 0) ? 1 : 2;
    #pragma unroll 1
    for (int kvs = 0; kvs < npass; ++kvs) {
        const u16* wh = wf + ((sec == 0) ? 0 : (96 + kvs * 96)) * 96;
        u16* dst = (sec == 0) ? (qpre + (size_t)b * 96 * HWn)
                              : (kvpre + (size_t)b * 192 * HWn + (size_t)kvs * 96 * HWn);

        f32x4 acc[3][4];
        #pragma unroll
        for (int m = 0; m < 3; ++m)
            #pragma unroll
            for (int n = 0; n < 4; ++n)
                acc[m][n] = (f32x4){0.f, 0.f, 0.f, 0.f};

        #pragma unroll 1
        for (int kt = 0; kt < 3; ++kt) {
            const int kb = kt * 32;
            f16x8 B[4];
            #pragma unroll
            for (int n = 0; n < 4; ++n)
                B[n] = *(const f16x8*)(xs + xoff(pxw + n * 16 + lr, (kb >> 3) + lg));
            f16x8 A[3];
            #pragma unroll
            for (int m = 0; m < 3; ++m)
                A[m] = *(const f16x8*)(wh + (oc0 + m * 16 + lr) * 96 + kb + lg * 8);
            #pragma unroll
            for (int m = 0; m < 3; ++m)
                #pragma unroll
                for (int n = 0; n < 4; ++n)
                    acc[m][n] = __builtin_amdgcn_mfma_f32_16x16x32_f16(A[m], B[n], acc[m][n], 0, 0, 0);
        }

        #pragma unroll
        for (int m = 0; m < 3; ++m) {
            #pragma unroll
            for (int i = 0; i < 4; ++i) {
                const int oc = oc0 + m * 16 + lg * 4 + i;
                u16* drow = dst + (size_t)oc * HWn + px0;
                #pragma unroll
                for (int n = 0; n < 4; ++n)
                    drow[pxw + n * 16 + lr] = f2h(acc[m][n][i]);
            }
        }
    }
}

// Packed-pair 3-tap conv for one row; accumulates into a[8] (f32 via dot2).
__device__ __forceinline__ void row3tap(
    const uint4 m, u32 lv, u32 rv, u32 w01, u32 w2z, float* a)
{
    const u32 P0 = m.x, P1 = m.y, P2 = m.z, P3 = m.w;
    const u32 s0 = (lv >> 16) | (P0 << 16);
    const u32 s1 = (P0 >> 16) | (P1 << 16);
    const u32 s2 = (P1 >> 16) | (P2 << 16);
    const u32 s3 = (P2 >> 16) | (P3 << 16);
    const u32 s4 = (P3 >> 16) | (rv << 16);
    a[0] = fdot2a(w2z, s1, fdot2a(w01, s0, a[0]));
    a[1] = fdot2a(w2z, P1, fdot2a(w01, P0, a[1]));
    a[2] = fdot2a(w2z, s2, fdot2a(w01, s1, a[2]));
    a[3] = fdot2a(w2z, P2, fdot2a(w01, P1, a[3]));
    a[4] = fdot2a(w2z, s3, fdot2a(w01, s2, a[4]));
    a[5] = fdot2a(w2z, P3, fdot2a(w01, P2, a[5]));
    a[6] = fdot2a(w2z, s4, fdot2a(w01, s3, a[6]));
    a[7] = fdot2a(w2z, rv, fdot2a(w01, P3, a[7]));
}

// K2a: depthwise 3x3 for q,k (192 planes) + ssq + S via MFMA. 128-px half-row
// tiles, 512 thr, 52 KB LDS, 1-deep load prefetch, direct atomics.
__global__ __launch_bounds__(512) void k_dw_qk(
    const u16* __restrict__ qpre, const u16* __restrict__ kvpre,
    const float* __restrict__ wqdw, const float* __restrict__ wkvdw,
    float* __restrict__ ssq, float* __restrict__ Sg)
{
    const int bid = blockIdx.x;                  // 0..2047
    const int wg = (bid & 7) * 256 + (bid >> 3); // XCD: contiguous y span per XCD
    const int b = wg >> 9;
    const int rem = wg & 511;
    const int y = rem >> 1;
    const int tx = (rem & 1) * 128;
    const int tid = threadIdx.x;
    const int lane = tid & 63;
    const int pq = tid >> 4;                     // 0..31 plane-within-iter
    const int chunk = tid & 15;
    const int x0l = chunk * 8;
    const int xg = tx + x0l;

    const bool vr0 = (y > 0), vr2 = (y < 255);
    const bool le = (chunk == 0) && (xg > 0);
    const bool re = (chunk == 15) && (xg + 8 < 256);

    __shared__ __align__(16) u16 qs[96][136];
    __shared__ __align__(16) u16 ks[96][136];

    auto addr = [&](int it, const u16*& src, const float*& wp, int& c, int& seg) {
        const int p = it * 32 + pq;              // 0..191
        if (p < 96) { c = p;      src = qpre  + ((size_t)(b * 96 + c)) * HWn;  wp = wqdw  + c * 9; seg = 0; }
        else        { c = p - 96; src = kvpre + ((size_t)(b * 192 + c)) * HWn; wp = wkvdw + c * 9; seg = 1; }
    };
    auto issue = [&](const u16* src, uint4* m, u32* el, u32* er) {
        const uint4 z = make_uint4(0u, 0u, 0u, 0u);
        const u16* r0 = src + (y - 1) * 256 + xg;
        const u16* r1 = r0 + 256;
        const u16* r2 = r1 + 256;
        m[0] = vr0 ? *reinterpret_cast<const uint4*>(r0) : z;
        m[1] = *reinterpret_cast<const uint4*>(r1);
        m[2] = vr2 ? *reinterpret_cast<const uint4*>(r2) : z;
        el[0] = (le && vr0) ? ((u32)r0[-1] << 16) : 0u;  er[0] = (re && vr0) ? (u32)r0[8] : 0u;
        el[1] = le ? ((u32)r1[-1] << 16) : 0u;           er[1] = re ? (u32)r1[8] : 0u;
        el[2] = (le && vr2) ? ((u32)r2[-1] << 16) : 0u;  er[2] = (re && vr2) ? (u32)r2[8] : 0u;
    };

    const u16* srcC; const float* wpC; int cC, segC;
    addr(0, srcC, wpC, cC, segC);
    uint4 mcur[3]; u32 elc[3], erc[3];
    issue(srcC, mcur, elc, erc);

    #pragma unroll 1
    for (int it = 0; it < 6; ++it) {
        const u16* srcN; const float* wpN; int cN, segN;
        uint4 mnx[3]; u32 eln[3], ern[3];
        if (it < 5) {
            addr(it + 1, srcN, wpN, cN, segN);
            issue(srcN, mnx, eln, ern);
        }

        float a[8] = {0.f, 0.f, 0.f, 0.f, 0.f, 0.f, 0.f, 0.f};
        #pragma unroll
        for (int r = 0; r < 3; ++r) {
            const u32 w01 = pack2h(wpC[r * 3 + 0], wpC[r * 3 + 1]);
            const u32 w2z = pack2h(wpC[r * 3 + 2], 0.f);
            const u32 lvn = __shfl((int)mcur[r].w, (lane - 1) & 63);
            const u32 rvn = __shfl((int)mcur[r].x, (lane + 1) & 63);
            const u32 lv = (chunk == 0)  ? elc[r] : lvn;
            const u32 rv = (chunk == 15) ? erc[r] : rvn;
            row3tap(mcur[r], lv, rv, w01, w2z, a);
        }

        const uint4 o = make_uint4(pack2h(a[0], a[1]), pack2h(a[2], a[3]),
                                   pack2h(a[4], a[5]), pack2h(a[6], a[7]));
        if (segC == 0) *reinterpret_cast<uint4*>(&qs[cC][x0l]) = o;
        else           *reinterpret_cast<uint4*>(&ks[cC][x0l]) = o;

        if (it < 5) {
            #pragma unroll
            for (int r = 0; r < 3; ++r) { mcur[r] = mnx[r]; elc[r] = eln[r]; erc[r] = ern[r]; }
            wpC = wpN; cC = cN; segC = segN;
        }
    }
    __syncthreads();

    // ssq: 192 rows x 2 halves (64 px) = 384 tasks
    if (tid < 384) {
        const int half = tid >= 192;
        const int r = tid - half * 192;
        const uint4* rr = reinterpret_cast<const uint4*>(
            (r < 96 ? &qs[r][0] : &ks[r - 96][0]) + half * 64);
        float s = 0.f;
        #pragma unroll
        for (int pch = 0; pch < 8; ++pch) {
            const uint4 a = rr[pch];
            s += sq2h(a.x) + sq2h(a.y) + sq2h(a.z) + sq2h(a.w);
        }
        atomicAdd(ssq + b * 192 + r, s);
    }

    // S via f16 MFMA: wave w -> head h = w&3, row-tile mt = w>>2.
    {
        const int w = tid >> 6;
        const int h = w & 3, mt = w >> 2;
        const int lr2 = lane & 15, lg2 = lane >> 4;
        const int ar = h * 24 + min(mt * 16 + lr2, 23);  // clamp-dup, discard on store
        f32x4 acc2[2];
        acc2[0] = (f32x4){0.f, 0.f, 0.f, 0.f};
        acc2[1] = (f32x4){0.f, 0.f, 0.f, 0.f};
        #pragma unroll
        for (int ks4 = 0; ks4 < 4; ++ks4) {
            const f16x8 A = *(const f16x8*)(&qs[ar][ks4 * 32 + lg2 * 8]);
            #pragma unroll
            for (int nt = 0; nt < 2; ++nt) {
                const int bc = h * 24 + min(nt * 16 + lr2, 23);
                const f16x8 B = *(const f16x8*)(&ks[bc][ks4 * 32 + lg2 * 8]);
                acc2[nt] = __builtin_amdgcn_mfma_f32_16x16x32_f16(A, B, acc2[nt], 0, 0, 0);
            }
        }
        #pragma unroll
        for (int nt = 0; nt < 2; ++nt) {
            const int col = nt * 16 + lr2;
            #pragma unroll
            for (int reg = 0; reg < 4; ++reg) {
                const int row24 = mt * 16 + lg2 * 4 + reg;
                if (row24 < 24 && col < 24)
                    atomicAdd(Sg + b * 2304 + h * 576 + row24 * 24 + col, acc2[nt][reg]);
            }
        }
    }
}

// K2b: depthwise 3x3 for v (96 planes), pure streaming: full 256-px rows,
// no LDS, no barrier, no edge loads (image borders are the only pads).
__global__ __launch_bounds__(512) void k_dw_v(
    const u16* __restrict__ kvpre, const float* __restrict__ wkvdw,
    u16* __restrict__ vout)
{
    const int bid = blockIdx.x;                  // 0..255 rows
    const int y = (bid & 7) * 32 + (bid >> 3);   // XCD: contiguous y span per XCD
    const int b = blockIdx.y;
    const int tid = threadIdx.x;
    const int lane = tid & 63;
    const int pl = tid >> 5;                     // 0..15 plane-within-iter
    const int chunk = tid & 31;
    const int x0 = chunk * 8;

    const bool vr0 = (y > 0), vr2 = (y < 255);

    auto issue = [&](int it, uint4* m) {
        const int c = it * 16 + pl;
        const u16* src = kvpre + ((size_t)(b * 192 + 96 + c)) * HWn;
        const uint4 z = make_uint4(0u, 0u, 0u, 0u);
        const u16* r0 = src + (y - 1) * 256 + x0;
        m[0] = vr0 ? *reinterpret_cast<const uint4*>(r0) : z;
        m[1] = *reinterpret_cast<const uint4*>(r0 + 256);
        m[2] = vr2 ? *reinterpret_cast<const uint4*>(r0 + 512) : z;
    };

    uint4 mcur[3];
    issue(0, mcur);

    #pragma unroll 1
    for (int it = 0; it < 6; ++it) {
        uint4 mnx[3];
        if (it < 5) issue(it + 1, mnx);

        const int c = it * 16 + pl;
        const float* wp = wkvdw + (96 + c) * 9;

        float a[8] = {0.f, 0.f, 0.f, 0.f, 0.f, 0.f, 0.f, 0.f};
        #pragma unroll
        for (int r = 0; r < 3; ++r) {
            const u32 w01 = pack2h(wp[r * 3 + 0], wp[r * 3 + 1]);
            const u32 w2z = pack2h(wp[r * 3 + 2], 0.f);
            const u32 lvn = __shfl((int)mcur[r].w, (lane - 1) & 63);
            const u32 rvn = __shfl((int)mcur[r].x, (lane + 1) & 63);
            const u32 lv = (chunk == 0)  ? 0u : lvn;   // image left edge
            const u32 rv = (chunk == 31) ? 0u : rvn;   // image right edge
            row3tap(mcur[r], lv, rv, w01, w2z, a);
        }

        const uint4 o = make_uint4(pack2h(a[0], a[1]), pack2h(a[2], a[3]),
                                   pack2h(a[4], a[5]), pack2h(a[6], a[7]));
        *reinterpret_cast<uint4*>(vout + ((size_t)(b * 96 + c)) * HWn + y * 256 + x0) = o;

        if (it < 5) {
            #pragma unroll
            for (int r = 0; r < 3; ++r) mcur[r] = mnx[r];
        }
    }
}

// K3: normalize, softmax, fold w_out with block-diag attn -> Mf [oc][dg] f16
__global__ __launch_bounds__(256) void k_attn_fold(
    const float* __restrict__ ssq, const float* __restrict__ S,
    const float* __restrict__ temp, const float* __restrict__ w_out,
    u16* __restrict__ mf)
{
    const int b = blockIdx.x;
    const int tid = threadIdx.x;
    __shared__ float rq[96], rk[96], att[2304];

    if (tid < 96) {
        rq[tid] = 1.f / fmaxf(sqrtf(ssq[b * 192 + tid]), 1e-12f);
    } else if (tid < 192) {
        const int c = tid - 96;
        rk[c] = 1.f / fmaxf(sqrtf(ssq[b * 192 + 96 + c]), 1e-12f);
    }
    __syncthreads();

    if (tid < 96) {
        const int h = tid / 24, i = tid % 24;
        const float tmp = temp[h];
        const float rqi = rq[h * 24 + i];
        float l[24];
        float m = -1e30f;
        #pragma unroll
        for (int j = 0; j < 24; ++j) {
            l[j] = S[b * 2304 + (h * 24 + i) * 24 + j] * rqi * rk[h * 24 + j] * tmp;
            m = fmaxf(m, l[j]);
        }
        float ssum = 0.f;
        #pragma unroll
        for (int j = 0; j < 24; ++j) { l[j] = expf(l[j] - m); ssum += l[j]; }
        const float inv = 1.f / ssum;
        #pragma unroll
        for (int j = 0; j < 24; ++j) att[(h * 24 + i) * 24 + j] = l[j] * inv;
    }
    __syncthreads();

    for (int k = 0; k < 36; ++k) {
        const int id = k * 256 + tid;
        const int dg = id / 96, oc = id % 96;
        const int h = dg / 24, d24 = dg % 24;
        float s = 0.f;
        #pragma unroll
        for (int i = 0; i < 24; ++i) {
            s += w_out[oc * 96 + h * 24 + i] * att[(h * 24 + i) * 24 + d24];
        }
        mf[b * 9216 + oc * 96 + dg] = f2h(s);
    }
}

// K4: out = M @ v via f16 MFMA. grid (512 px-tiles, 4 b), 256 thr, 32 KB LDS.
__global__ __launch_bounds__(256, 5) void k_out_mfma(
    const u16* __restrict__ v, const u16* __restrict__ mf,
    float* __restrict__ out)
{
    const int b = blockIdx.y;
    const int px0 = blockIdx.x * 128;
    const int tid = threadIdx.x;
    __shared__ __align__(16) u16 xt[16384];

    const u16* vb = v + (size_t)b * 96 * HWn;
    const u16* mh = mf + b * 9216;

    const int icq = (tid >> 4) * 2;
    const int pxs = (tid & 15) * 8;
    #pragma unroll 1
    for (int p = 0; p < 3; ++p) {
        const int dg = p * 32 + icq;
        const uint4 u0 = *reinterpret_cast<const uint4*>(vb + (size_t)dg * HWn + px0 + pxs);
        const uint4 u1 = *reinterpret_cast<const uint4*>(vb + (size_t)(dg + 1) * HWn + px0 + pxs);
        const u32 w0[4] = {u0.x, u0.y, u0.z, u0.w};
        const u32 w1[4] = {u1.x, u1.y, u1.z, u1.w};
        const int icb = dg >> 3, icl = dg & 7;
        #pragma unroll
        for (int j = 0; j < 8; ++j) {
            const u32 lo = (w0[j >> 1] >> ((j & 1) * 16)) & 0xffffu;
            const u32 hi = (w1[j >> 1] >> ((j & 1) * 16)) & 0xffffu;
            const int o = xoff(pxs + j, icb) + icl;      // even
            *reinterpret_cast<u32*>(&xt[o]) = (hi << 16) | lo;
        }
    }
    __syncthreads();

    const int lane = tid & 63;
    const int wv = tid >> 6;
    const int oc0 = (wv >> 1) * 48;
    const int pxw = (wv & 1) * 64;
    const int lr = lane & 15, lg = lane >> 4;

    f32x4 acc[3][4];
    #pragma unroll
    for (int m = 0; m < 3; ++m)
        #pragma unroll
        for (int n = 0; n < 4; ++n)
            acc[m][n] = (f32x4){0.f, 0.f, 0.f, 0.f};

    #pragma unroll 1
    for (int kt = 0; kt < 3; ++kt) {
        const int kb = kt * 32;
        f16x8 B[4];
        #pragma unroll
        for (int n = 0; n < 4; ++n)
            B[n] = *(const f16x8*)(xt + xoff(pxw + n * 16 + lr, (kb >> 3) + lg));
        f16x8 A[3];
        #pragma unroll
        for (int m = 0; m < 3; ++m)
            A[m] = *(const f16x8*)(mh + (oc0 + m * 16 + lr) * 96 + kb + lg * 8);
        #pragma unroll
        for (int m = 0; m < 3; ++m)
            #pragma unroll
            for (int n = 0; n < 4; ++n)
                acc[m][n] = __builtin_amdgcn_mfma_f32_16x16x32_f16(A[m], B[n], acc[m][n], 0, 0, 0);
    }

    #pragma unroll
    for (int m = 0; m < 3; ++m) {
        #pragma unroll
        for (int i = 0; i < 4; ++i) {
            const int oc = oc0 + m * 16 + lg * 4 + i;
            float* drow = out + ((size_t)(b * 96 + oc)) * HWn + px0;
            #pragma unroll
            for (int n = 0; n < 4; ++n)
                drow[pxw + n * 16 + lr] = acc[m][n][i];
        }
    }
}

extern "C" void kernel_launch(void* const* d_in, const int* in_sizes, int n_in,
                              void* d_out, int out_size, void* d_ws, size_t ws_size,
                              hipStream_t stream) {
    (void)in_sizes; (void)n_in; (void)out_size; (void)ws_size;
    const float* x      = (const float*)d_in[0];
    const float* ff     = (const float*)d_in[1];
    const float* w_q    = (const float*)d_in[2];
    const float* w_kv   = (const float*)d_in[3];
    const float* w_q_dw = (const float*)d_in[4];
    const float* w_kv_dw= (const float*)d_in[5];
    const float* w_out  = (const float*)d_in[6];
    const float* temp   = (const float*)d_in[7];
    float* out = (float*)d_out;

    char* ws = (char*)d_ws;
    u16* qpre   = (u16*)(ws);                      //  50,331,648 B
    u16* kvpre  = (u16*)(ws + 50331648);           // 100,663,296 B
    u16* vbuf   = (u16*)(ws + 150994944);          //  50,331,648 B
    float* ssq  = (float*)(ws + 201326592);        //       3,072 B
    float* S    = (float*)(ws + 201329664);        //      36,864 B
    u16* wf     = (u16*)(ws + 201366528);          //      55,296 B
    u16* mf     = (u16*)(ws + 201421824);          //      73,728 B

    hipMemsetAsync(ws + 201326592, 0, 3072 + 36864, stream);

    k_prep_w<<<108, 256, 0, stream>>>(w_q, w_kv, wf);
    k_conv_mfma<<<dim3(512, 2, 4), 256, 0, stream>>>(ff, x, wf, qpre, kvpre);
    k_dw_qk<<<dim3(2048), 512, 0, stream>>>(qpre, kvpre, w_q_dw, w_kv_dw, ssq, S);
    k_dw_v<<<dim3(256, 4), 512, 0, stream>>>(kvpre, w_kv_dw, vbuf);
    k_attn_fold<<<4, 256, 0, stream>>>(ssq, S, temp, w_out, mf);
    k_out_mfma<<<dim3(512, 4), 256, 0, stream>>>(vbuf, mf, out);
}

// Round 9
// 257.037 us; speedup vs baseline: 1.1932x; 1.0619x over previous
//
#include <hip/hip_runtime.h>
#include <hip/hip_bf16.h>
#include <hip/hip_fp16.h>

typedef unsigned int u32;
typedef unsigned short u16;
typedef _Float16 f16;

static constexpr int HWn = 65536;

typedef __attribute__((ext_vector_type(8))) f16 f16x8;
typedef __attribute__((ext_vector_type(2))) f16 f16x2;
typedef __attribute__((ext_vector_type(4))) float f32x4;

__device__ __forceinline__ float h2f(u16 u) {
    union { u16 s; f16 h; } z; z.s = u; return (float)z.h;
}
__device__ __forceinline__ u16 f2h(float f) {
    union { u16 s; f16 h; } z; z.h = (f16)f; return z.s;
}
__device__ __forceinline__ u32 pack2h(float a, float b) {
    union { u32 i; f16 h[2]; } z; z.h[0] = (f16)a; z.h[1] = (f16)b; return z.i;
}
__device__ __forceinline__ float hlo(u32 u) {
    union { u32 i; f16 h[2]; } z; z.i = u; return (float)z.h[0];
}
__device__ __forceinline__ float hhi(u32 u) {
    union { u32 i; f16 h[2]; } z; z.i = u; return (float)z.h[1];
}
__device__ __forceinline__ float sq2h(u32 a) {
    const float l = hlo(a), h = hhi(a);
    return fmaf(l, l, h * h);
}

#if defined(__has_builtin)
#if __has_builtin(__builtin_amdgcn_fdot2)
#define HAS_FDOT2 1
#endif
#endif
__device__ __forceinline__ float fdot2a(u32 a, u32 b, float c) {
#ifdef HAS_FDOT2
    union { u32 i; f16x2 h; } A, B; A.i = a; B.i = b;
    return __builtin_amdgcn_fdot2(A.h, B.h, c, false);
#else
    return fmaf(hlo(a), hlo(b), fmaf(hhi(a), hhi(b), c));
#endif
}

// Swizzled LDS offset (u16 units) for transposed X tile: [px 0..127][ic 0..95]
__device__ __forceinline__ int xoff(int px, int icb) {
    return px * 128 + (((icb ^ (px & 7) ^ ((px >> 3) & 7))) << 3);
}

// Convert conv1x1 weights to f16, layout [row 0..287][ic 0..95]
__global__ __launch_bounds__(256) void k_prep_w(
    const float* __restrict__ wq, const float* __restrict__ wkv,
    u16* __restrict__ wf)
{
    const int i = blockIdx.x * 256 + threadIdx.x;
    if (i >= 288 * 96) return;
    const int row = i / 96, ic = i % 96;
    const float w = (row < 96) ? wq[row * 96 + ic] : wkv[(row - 96) * 96 + ic];
    wf[i] = f2h(w);
}

// K1: conv1x1 via f16 MFMA, 2-tile pipelined (issue T1 loads during T0 compute).
// grid (256 double-tiles, 2 sec {q, kv}, 4 b), 256 thr, 32 KB LDS.
__global__ __launch_bounds__(256, 3) void k_conv_mfma(
    const float* __restrict__ ff, const float* __restrict__ x,
    const u16* __restrict__ wf,
    u16* __restrict__ qpre, u16* __restrict__ kvpre)
{
    const int b = blockIdx.z, sec = blockIdx.y;
    const int pxb = blockIdx.x * 256;
    const int tid = threadIdx.x;

    __shared__ __align__(16) u16 xs[16384];     // 32 KB, f16 bits

    const float* src = (sec == 0 ? ff : x) + (size_t)b * 96 * HWn;
    const int icq = (tid >> 4) * 2;
    const int pxs = (tid & 15) * 8;
    const int lane = tid & 63;
    const int wv = tid >> 6;
    const int oc0 = (wv >> 1) * 48;
    const int pxw = (wv & 1) * 64;
    const int lr = lane & 15, lg = lane >> 4;

    float4 L[12];

    auto issue = [&](int px0) {
        #pragma unroll
        for (int p = 0; p < 3; ++p) {
            const float* rp0 = src + (size_t)(p * 32 + icq) * HWn + px0 + pxs;
            const float* rp1 = rp0 + HWn;
            L[p * 4 + 0] = *reinterpret_cast<const float4*>(rp0);
            L[p * 4 + 1] = *reinterpret_cast<const float4*>(rp0 + 4);
            L[p * 4 + 2] = *reinterpret_cast<const float4*>(rp1);
            L[p * 4 + 3] = *reinterpret_cast<const float4*>(rp1 + 4);
        }
    };
    auto stage = [&]() {
        #pragma unroll
        for (int p = 0; p < 3; ++p) {
            const int ic = p * 32 + icq;
            const int icb = ic >> 3, icl = ic & 7;
            const float e0[8] = {L[p*4+0].x, L[p*4+0].y, L[p*4+0].z, L[p*4+0].w,
                                 L[p*4+1].x, L[p*4+1].y, L[p*4+1].z, L[p*4+1].w};
            const float e1[8] = {L[p*4+2].x, L[p*4+2].y, L[p*4+2].z, L[p*4+2].w,
                                 L[p*4+3].x, L[p*4+3].y, L[p*4+3].z, L[p*4+3].w};
            #pragma unroll
            for (int j = 0; j < 8; ++j) {
                const int o = xoff(pxs + j, icb) + icl;   // even
                *reinterpret_cast<u32*>(&xs[o]) = pack2h(e0[j], e1[j]);
            }
        }
    };
    auto compute = [&](int px0) {
        const int npass = (sec == 0) ? 1 : 2;
        #pragma unroll 1
        for (int kvs = 0; kvs < npass; ++kvs) {
            const u16* wh = wf + ((sec == 0) ? 0 : (96 + kvs * 96)) * 96;
            u16* dst = (sec == 0) ? (qpre + (size_t)b * 96 * HWn)
                                  : (kvpre + (size_t)b * 192 * HWn + (size_t)kvs * 96 * HWn);
            f32x4 acc[3][4];
            #pragma unroll
            for (int m = 0; m < 3; ++m)
                #pragma unroll
                for (int n = 0; n < 4; ++n)
                    acc[m][n] = (f32x4){0.f, 0.f, 0.f, 0.f};

            #pragma unroll 1
            for (int kt = 0; kt < 3; ++kt) {
                const int kb = kt * 32;
                f16x8 B[4];
                #pragma unroll
                for (int n = 0; n < 4; ++n)
                    B[n] = *(const f16x8*)(xs + xoff(pxw + n * 16 + lr, (kb >> 3) + lg));
                f16x8 A[3];
                #pragma unroll
                for (int m = 0; m < 3; ++m)
                    A[m] = *(const f16x8*)(wh + (oc0 + m * 16 + lr) * 96 + kb + lg * 8);
                #pragma unroll
                for (int m = 0; m < 3; ++m)
                    #pragma unroll
                    for (int n = 0; n < 4; ++n)
                        acc[m][n] = __builtin_amdgcn_mfma_f32_16x16x32_f16(A[m], B[n], acc[m][n], 0, 0, 0);
            }

            #pragma unroll
            for (int m = 0; m < 3; ++m) {
                #pragma unroll
                for (int i = 0; i < 4; ++i) {
                    const int oc = oc0 + m * 16 + lg * 4 + i;
                    u16* drow = dst + (size_t)oc * HWn + px0;
                    #pragma unroll
                    for (int n = 0; n < 4; ++n)
                        drow[pxw + n * 16 + lr] = f2h(acc[m][n][i]);
                }
            }
        }
    };

    issue(pxb);
    stage();
    __syncthreads();
    issue(pxb + 128);        // T1 loads in flight during T0 compute
    compute(pxb);
    __syncthreads();         // all waves done reading xs
    stage();                 // T1 (loads have landed by now)
    __syncthreads();
    compute(pxb + 128);
}

// Packed-pair 3-tap conv for one row; accumulates into a[8] (f32 via dot2).
__device__ __forceinline__ void row3tap(
    const uint4 m, u32 lv, u32 rv, u32 w01, u32 w2z, float* a)
{
    const u32 P0 = m.x, P1 = m.y, P2 = m.z, P3 = m.w;
    const u32 s0 = (lv >> 16) | (P0 << 16);
    const u32 s1 = (P0 >> 16) | (P1 << 16);
    const u32 s2 = (P1 >> 16) | (P2 << 16);
    const u32 s3 = (P2 >> 16) | (P3 << 16);
    const u32 s4 = (P3 >> 16) | (rv << 16);
    a[0] = fdot2a(w2z, s1, fdot2a(w01, s0, a[0]));
    a[1] = fdot2a(w2z, P1, fdot2a(w01, P0, a[1]));
    a[2] = fdot2a(w2z, s2, fdot2a(w01, s1, a[2]));
    a[3] = fdot2a(w2z, P2, fdot2a(w01, P1, a[3]));
    a[4] = fdot2a(w2z, s3, fdot2a(w01, s2, a[4]));
    a[5] = fdot2a(w2z, P3, fdot2a(w01, P2, a[5]));
    a[6] = fdot2a(w2z, s4, fdot2a(w01, s3, a[6]));
    a[7] = fdot2a(w2z, rv, fdot2a(w01, P3, a[7]));
}

// K2a: depthwise 3x3 for q,k (192 planes) + ssq + S via MFMA (unchanged from R8).
__global__ __launch_bounds__(512) void k_dw_qk(
    const u16* __restrict__ qpre, const u16* __restrict__ kvpre,
    const float* __restrict__ wqdw, const float* __restrict__ wkvdw,
    float* __restrict__ ssq, float* __restrict__ Sg)
{
    const int bid = blockIdx.x;                  // 0..2047
    const int wg = (bid & 7) * 256 + (bid >> 3); // XCD: contiguous y span per XCD
    const int b = wg >> 9;
    const int rem = wg & 511;
    const int y = rem >> 1;
    const int tx = (rem & 1) * 128;
    const int tid = threadIdx.x;
    const int lane = tid & 63;
    const int pq = tid >> 4;                     // 0..31 plane-within-iter
    const int chunk = tid & 15;
    const int x0l = chunk * 8;
    const int xg = tx + x0l;

    const bool vr0 = (y > 0), vr2 = (y < 255);
    const bool le = (chunk == 0) && (xg > 0);
    const bool re = (chunk == 15) && (xg + 8 < 256);

    __shared__ __align__(16) u16 qs[96][136];
    __shared__ __align__(16) u16 ks[96][136];

    auto addr = [&](int it, const u16*& src, const float*& wp, int& c, int& seg) {
        const int p = it * 32 + pq;              // 0..191
        if (p < 96) { c = p;      src = qpre  + ((size_t)(b * 96 + c)) * HWn;  wp = wqdw  + c * 9; seg = 0; }
        else        { c = p - 96; src = kvpre + ((size_t)(b * 192 + c)) * HWn; wp = wkvdw + c * 9; seg = 1; }
    };
    auto issue = [&](const u16* src, uint4* m, u32* el, u32* er) {
        const uint4 z = make_uint4(0u, 0u, 0u, 0u);
        const u16* r0 = src + (y - 1) * 256 + xg;
        const u16* r1 = r0 + 256;
        const u16* r2 = r1 + 256;
        m[0] = vr0 ? *reinterpret_cast<const uint4*>(r0) : z;
        m[1] = *reinterpret_cast<const uint4*>(r1);
        m[2] = vr2 ? *reinterpret_cast<const uint4*>(r2) : z;
        el[0] = (le && vr0) ? ((u32)r0[-1] << 16) : 0u;  er[0] = (re && vr0) ? (u32)r0[8] : 0u;
        el[1] = le ? ((u32)r1[-1] << 16) : 0u;           er[1] = re ? (u32)r1[8] : 0u;
        el[2] = (le && vr2) ? ((u32)r2[-1] << 16) : 0u;  er[2] = (re && vr2) ? (u32)r2[8] : 0u;
    };

    const u16* srcC; const float* wpC; int cC, segC;
    addr(0, srcC, wpC, cC, segC);
    uint4 mcur[3]; u32 elc[3], erc[3];
    issue(srcC, mcur, elc, erc);

    #pragma unroll 1
    for (int it = 0; it < 6; ++it) {
        const u16* srcN; const float* wpN; int cN, segN;
        uint4 mnx[3]; u32 eln[3], ern[3];
        if (it < 5) {
            addr(it + 1, srcN, wpN, cN, segN);
            issue(srcN, mnx, eln, ern);
        }

        float a[8] = {0.f, 0.f, 0.f, 0.f, 0.f, 0.f, 0.f, 0.f};
        #pragma unroll
        for (int r = 0; r < 3; ++r) {
            const u32 w01 = pack2h(wpC[r * 3 + 0], wpC[r * 3 + 1]);
            const u32 w2z = pack2h(wpC[r * 3 + 2], 0.f);
            const u32 lvn = __shfl((int)mcur[r].w, (lane - 1) & 63);
            const u32 rvn = __shfl((int)mcur[r].x, (lane + 1) & 63);
            const u32 lv = (chunk == 0)  ? elc[r] : lvn;
            const u32 rv = (chunk == 15) ? erc[r] : rvn;
            row3tap(mcur[r], lv, rv, w01, w2z, a);
        }

        const uint4 o = make_uint4(pack2h(a[0], a[1]), pack2h(a[2], a[3]),
                                   pack2h(a[4], a[5]), pack2h(a[6], a[7]));
        if (segC == 0) *reinterpret_cast<uint4*>(&qs[cC][x0l]) = o;
        else           *reinterpret_cast<uint4*>(&ks[cC][x0l]) = o;

        if (it < 5) {
            #pragma unroll
            for (int r = 0; r < 3; ++r) { mcur[r] = mnx[r]; elc[r] = eln[r]; erc[r] = ern[r]; }
            wpC = wpN; cC = cN; segC = segN;
        }
    }
    __syncthreads();

    if (tid < 384) {
        const int half = tid >= 192;
        const int r = tid - half * 192;
        const uint4* rr = reinterpret_cast<const uint4*>(
            (r < 96 ? &qs[r][0] : &ks[r - 96][0]) + half * 64);
        float s = 0.f;
        #pragma unroll
        for (int pch = 0; pch < 8; ++pch) {
            const uint4 a = rr[pch];
            s += sq2h(a.x) + sq2h(a.y) + sq2h(a.z) + sq2h(a.w);
        }
        atomicAdd(ssq + b * 192 + r, s);
    }

    {
        const int w = tid >> 6;
        const int h = w & 3, mt = w >> 2;
        const int lr2 = lane & 15, lg2 = lane >> 4;
        const int ar = h * 24 + min(mt * 16 + lr2, 23);  // clamp-dup, discard on store
        f32x4 acc2[2];
        acc2[0] = (f32x4){0.f, 0.f, 0.f, 0.f};
        acc2[1] = (f32x4){0.f, 0.f, 0.f, 0.f};
        #pragma unroll
        for (int ks4 = 0; ks4 < 4; ++ks4) {
            const f16x8 A = *(const f16x8*)(&qs[ar][ks4 * 32 + lg2 * 8]);
            #pragma unroll
            for (int nt = 0; nt < 2; ++nt) {
                const int bc = h * 24 + min(nt * 16 + lr2, 23);
                const f16x8 B = *(const f16x8*)(&ks[bc][ks4 * 32 + lg2 * 8]);
                acc2[nt] = __builtin_amdgcn_mfma_f32_16x16x32_f16(A, B, acc2[nt], 0, 0, 0);
            }
        }
        #pragma unroll
        for (int nt = 0; nt < 2; ++nt) {
            const int col = nt * 16 + lr2;
            #pragma unroll
            for (int reg = 0; reg < 4; ++reg) {
                const int row24 = mt * 16 + lg2 * 4 + reg;
                if (row24 < 24 && col < 24)
                    atomicAdd(Sg + b * 2304 + h * 576 + row24 * 24 + col, acc2[nt][reg]);
            }
        }
    }
}

// K3: normalize, softmax, fold w_out with block-diag attn -> Mf [oc][dg] f16
__global__ __launch_bounds__(256) void k_attn_fold(
    const float* __restrict__ ssq, const float* __restrict__ S,
    const float* __restrict__ temp, const float* __restrict__ w_out,
    u16* __restrict__ mf)
{
    const int b = blockIdx.x;
    const int tid = threadIdx.x;
    __shared__ float rq[96], rk[96], att[2304];

    if (tid < 96) {
        rq[tid] = 1.f / fmaxf(sqrtf(ssq[b * 192 + tid]), 1e-12f);
    } else if (tid < 192) {
        const int c = tid - 96;
        rk[c] = 1.f / fmaxf(sqrtf(ssq[b * 192 + 96 + c]), 1e-12f);
    }
    __syncthreads();

    if (tid < 96) {
        const int h = tid / 24, i = tid % 24;
        const float tmp = temp[h];
        const float rqi = rq[h * 24 + i];
        float l[24];
        float m = -1e30f;
        #pragma unroll
        for (int j = 0; j < 24; ++j) {
            l[j] = S[b * 2304 + (h * 24 + i) * 24 + j] * rqi * rk[h * 24 + j] * tmp;
            m = fmaxf(m, l[j]);
        }
        float ssum = 0.f;
        #pragma unroll
        for (int j = 0; j < 24; ++j) { l[j] = expf(l[j] - m); ssum += l[j]; }
        const float inv = 1.f / ssum;
        #pragma unroll
        for (int j = 0; j < 24; ++j) att[(h * 24 + i) * 24 + j] = l[j] * inv;
    }
    __syncthreads();

    for (int k = 0; k < 36; ++k) {
        const int id = k * 256 + tid;
        const int dg = id / 96, oc = id % 96;
        const int h = dg / 24, d24 = dg % 24;
        float s = 0.f;
        #pragma unroll
        for (int i = 0; i < 24; ++i) {
            s += w_out[oc * 96 + h * 24 + i] * att[(h * 24 + i) * 24 + d24];
        }
        mf[b * 9216 + oc * 96 + dg] = f2h(s);
    }
}

// K4: fused v-dwconv + out-GEMM. Per (half-row, batch) block: dwconv the 96
// v-planes into swizzled LDS (v never hits HBM), then out = M @ v via MFMA.
// grid 2048, 256 thr, 32 KB LDS.
__global__ __launch_bounds__(256, 4) void k_v_out(
    const u16* __restrict__ kvpre, const float* __restrict__ wkvdw,
    const u16* __restrict__ mf, float* __restrict__ out)
{
    const int bid = blockIdx.x;                  // 0..2047
    const int wg = (bid & 7) * 256 + (bid >> 3); // XCD: contiguous y span per XCD
    const int b = wg >> 9;
    const int rem = wg & 511;
    const int y = rem >> 1;
    const int tx = (rem & 1) * 128;
    const int tid = threadIdx.x;
    const int lane = tid & 63;
    const int slot = tid >> 4;                   // 0..15 dg-pair slot
    const int chunk = tid & 15;
    const int x0l = chunk * 8;
    const int xg = tx + x0l;

    const bool vr0 = (y > 0), vr2 = (y < 255);
    const bool le = (chunk == 0) && (xg > 0);
    const bool re = (chunk == 15) && (xg + 8 < 256);

    __shared__ __align__(16) u16 xt[16384];

    auto issue = [&](int it, uint4* m0, uint4* m1, u32* e0l, u32* e0r, u32* e1l, u32* e1r) {
        const int dg = (it * 16 + slot) * 2;
        const u16* s0 = kvpre + ((size_t)(b * 192 + 96 + dg)) * HWn + (y - 1) * 256 + xg;
        const u16* s1 = s0 + HWn;
        const uint4 z = make_uint4(0u, 0u, 0u, 0u);
        m0[0] = vr0 ? *reinterpret_cast<const uint4*>(s0)       : z;
        m0[1] =       *reinterpret_cast<const uint4*>(s0 + 256);
        m0[2] = vr2 ? *reinterpret_cast<const uint4*>(s0 + 512) : z;
        m1[0] = vr0 ? *reinterpret_cast<const uint4*>(s1)       : z;
        m1[1] =       *reinterpret_cast<const uint4*>(s1 + 256);
        m1[2] = vr2 ? *reinterpret_cast<const uint4*>(s1 + 512) : z;
        e0l[0] = (le && vr0) ? ((u32)s0[-1] << 16) : 0u;   e0r[0] = (re && vr0) ? (u32)s0[8] : 0u;
        e0l[1] = le ? ((u32)s0[255] << 16) : 0u;           e0r[1] = re ? (u32)s0[264] : 0u;
        e0l[2] = (le && vr2) ? ((u32)s0[511] << 16) : 0u;  e0r[2] = (re && vr2) ? (u32)s0[520] : 0u;
        e1l[0] = (le && vr0) ? ((u32)s1[-1] << 16) : 0u;   e1r[0] = (re && vr0) ? (u32)s1[8] : 0u;
        e1l[1] = le ? ((u32)s1[255] << 16) : 0u;           e1r[1] = re ? (u32)s1[264] : 0u;
        e1l[2] = (le && vr2) ? ((u32)s1[511] << 16) : 0u;  e1r[2] = (re && vr2) ? (u32)s1[520] : 0u;
    };

    uint4 m0c[3], m1c[3]; u32 e0lc[3], e0rc[3], e1lc[3], e1rc[3];
    issue(0, m0c, m1c, e0lc, e0rc, e1lc, e1rc);

    #pragma unroll 1
    for (int it = 0; it < 3; ++it) {
        uint4 m0n[3], m1n[3]; u32 e0ln[3], e0rn[3], e1ln[3], e1rn[3];
        if (it < 2) issue(it + 1, m0n, m1n, e0ln, e0rn, e1ln, e1rn);

        const int dg = (it * 16 + slot) * 2;
        const float* wp0 = wkvdw + (96 + dg) * 9;
        const float* wp1 = wp0 + 9;

        float a0[8] = {0.f, 0.f, 0.f, 0.f, 0.f, 0.f, 0.f, 0.f};
        float a1[8] = {0.f, 0.f, 0.f, 0.f, 0.f, 0.f, 0.f, 0.f};
        #pragma unroll
        for (int r = 0; r < 3; ++r) {
            {
                const u32 w01 = pack2h(wp0[r * 3 + 0], wp0[r * 3 + 1]);
                const u32 w2z = pack2h(wp0[r * 3 + 2], 0.f);
                const u32 lvn = __shfl((int)m0c[r].w, (lane - 1) & 63);
                const u32 rvn = __shfl((int)m0c[r].x, (lane + 1) & 63);
                const u32 lv = (chunk == 0)  ? e0lc[r] : lvn;
                const u32 rv = (chunk == 15) ? e0rc[r] : rvn;
                row3tap(m0c[r], lv, rv, w01, w2z, a0);
            }
            {
                const u32 w01 = pack2h(wp1[r * 3 + 0], wp1[r * 3 + 1]);
                const u32 w2z = pack2h(wp1[r * 3 + 2], 0.f);
                const u32 lvn = __shfl((int)m1c[r].w, (lane - 1) & 63);
                const u32 rvn = __shfl((int)m1c[r].x, (lane + 1) & 63);
                const u32 lv = (chunk == 0)  ? e1lc[r] : lvn;
                const u32 rv = (chunk == 15) ? e1rc[r] : rvn;
                row3tap(m1c[r], lv, rv, w01, w2z, a1);
            }
        }

        const int icb = dg >> 3, icl = dg & 7;   // even
        #pragma unroll
        for (int j = 0; j < 8; ++j) {
            *reinterpret_cast<u32*>(&xt[xoff(x0l + j, icb) + icl]) = pack2h(a0[j], a1[j]);
        }

        if (it < 2) {
            #pragma unroll
            for (int r = 0; r < 3; ++r) {
                m0c[r] = m0n[r]; m1c[r] = m1n[r];
                e0lc[r] = e0ln[r]; e0rc[r] = e0rn[r];
                e1lc[r] = e1ln[r]; e1rc[r] = e1rn[r];
            }
        }
    }
    __syncthreads();

    // out = M @ v for this 128-px strip
    const u16* mh = mf + b * 9216;
    const int wv = tid >> 6;
    const int oc0 = (wv >> 1) * 48;
    const int pxw = (wv & 1) * 64;
    const int lr = lane & 15, lg = lane >> 4;

    f32x4 acc[3][4];
    #pragma unroll
    for (int m = 0; m < 3; ++m)
        #pragma unroll
        for (int n = 0; n < 4; ++n)
            acc[m][n] = (f32x4){0.f, 0.f, 0.f, 0.f};

    #pragma unroll 1
    for (int kt = 0; kt < 3; ++kt) {
        const int kb = kt * 32;
        f16x8 B[4];
        #pragma unroll
        for (int n = 0; n < 4; ++n)
            B[n] = *(const f16x8*)(xt + xoff(pxw + n * 16 + lr, (kb >> 3) + lg));
        f16x8 A[3];
        #pragma unroll
        for (int m = 0; m < 3; ++m)
            A[m] = *(const f16x8*)(mh + (oc0 + m * 16 + lr) * 96 + kb + lg * 8);
        #pragma unroll
        for (int m = 0; m < 3; ++m)
            #pragma unroll
            for (int n = 0; n < 4; ++n)
                acc[m][n] = __builtin_amdgcn_mfma_f32_16x16x32_f16(A[m], B[n], acc[m][n], 0, 0, 0);
    }

    #pragma unroll
    for (int m = 0; m < 3; ++m) {
        #pragma unroll
        for (int i = 0; i < 4; ++i) {
            const int oc = oc0 + m * 16 + lg * 4 + i;
            float* drow = out + ((size_t)(b * 96 + oc)) * HWn + y * 256 + tx;
            #pragma unroll
            for (int n = 0; n < 4; ++n)
                drow[pxw + n * 16 + lr] = acc[m][n][i];
        }
    }
}

extern "C" void kernel_launch(void* const* d_in, const int* in_sizes, int n_in,
                              void* d_out, int out_size, void* d_ws, size_t ws_size,
                              hipStream_t stream) {
    (void)in_sizes; (void)n_in; (void)out_size; (void)ws_size;
    const float* x      = (const float*)d_in[0];
    const float* ff     = (const float*)d_in[1];
    const float* w_q    = (const float*)d_in[2];
    const float* w_kv   = (const float*)d_in[3];
    const float* w_q_dw = (const float*)d_in[4];
    const float* w_kv_dw= (const float*)d_in[5];
    const float* w_out  = (const float*)d_in[6];
    const float* temp   = (const float*)d_in[7];
    float* out = (float*)d_out;

    char* ws = (char*)d_ws;
    u16* qpre   = (u16*)(ws);                      //  50,331,648 B
    u16* kvpre  = (u16*)(ws + 50331648);           // 100,663,296 B
    float* ssq  = (float*)(ws + 150994944);        //       3,072 B
    float* S    = (float*)(ws + 150998016);        //      36,864 B
    u16* wf     = (u16*)(ws + 151034880);          //      55,296 B
    u16* mf     = (u16*)(ws + 151090176);          //      73,728 B

    hipMemsetAsync(ws + 150994944, 0, 3072 + 36864, stream);

    k_prep_w<<<108, 256, 0, stream>>>(w_q, w_kv, wf);
    k_conv_mfma<<<dim3(256, 2, 4), 256, 0, stream>>>(ff, x, wf, qpre, kvpre);
    k_dw_qk<<<dim3(2048), 512, 0, stream>>>(qpre, kvpre, w_q_dw, w_kv_dw, ssq, S);
    k_attn_fold<<<4, 256, 0, stream>>>(ssq, S, temp, w_out, mf);
    k_v_out<<<dim3(2048), 256, 0, stream>>>(kvpre, w_kv_dw, mf, out);
}